// Round 3
// baseline (300.221 us; speedup 1.0000x reference)
//
#include <hip/hip_runtime.h>
#include <hip/hip_bf16.h>

#define N 8192
#define D 128
#define NWAVES 4
#define KVSPLIT (N / NWAVES)   // 2048 keys per wave
#define KVBLK 64

typedef __attribute__((ext_vector_type(8))) _Float16 half8;
typedef __attribute__((ext_vector_type(4))) float f32x4;

// ---- preprocessing: fp32 -> fp16 (row-major) ----
__global__ void cvt_f16_4(const float4* __restrict__ src, _Float16* __restrict__ dst, int n4) {
    int i = blockIdx.x * 256 + threadIdx.x;
    if (i < n4) {
        float4 v = src[i];
        _Float16 o0 = (_Float16)v.x, o1 = (_Float16)v.y, o2 = (_Float16)v.z, o3 = (_Float16)v.w;
        ushort4 o;
        o.x = __builtin_bit_cast(ushort, o0);
        o.y = __builtin_bit_cast(ushort, o1);
        o.z = __builtin_bit_cast(ushort, o2);
        o.w = __builtin_bit_cast(ushort, o3);
        *reinterpret_cast<ushort4*>(dst + i * 4) = o;
    }
}

// ---- preprocessing: V [N][D] fp32 -> Vt [D][N] fp16 (tiled transpose) ----
__global__ void transpose_v(const float* __restrict__ V, _Float16* __restrict__ Vt) {
    __shared__ _Float16 tile[64][65];
    const int k0 = blockIdx.x * 64;
    const int d0 = blockIdx.y * 64;
    const int tid = threadIdx.x;
#pragma unroll
    for (int p = 0; p < 16; ++p) {
        int flat = p * 256 + tid;
        int r = flat >> 6, c = flat & 63;
        tile[r][c] = (_Float16)(V[(k0 + r) * D + d0 + c]);
    }
    __syncthreads();
#pragma unroll
    for (int p = 0; p < 16; ++p) {
        int flat = p * 256 + tid;
        int dd = flat >> 6, k = flat & 63;
        Vt[(d0 + dd) * N + k0 + k] = tile[k][dd];
    }
}

// ---- main flash-attention kernel ----
// grid = 512 blocks (16 q-rows each), 4 waves split the KV range.
__launch_bounds__(256)
__global__ void fa_kernel(const _Float16* __restrict__ Qh, const _Float16* __restrict__ Kh,
                          const _Float16* __restrict__ Vt, float* __restrict__ O) {
    __shared__ _Float16 plds[NWAVES][16 * 64];    // P transpose buffer, swizzled (8 KB)
    __shared__ float o_lds[NWAVES][16][128];      // partial O (32 KB)
    __shared__ float m_lds[NWAVES][16];
    __shared__ float l_lds[NWAVES][16];

    const int tid  = threadIdx.x;
    const int w    = tid >> 6;
    const int lane = tid & 63;
    const int g    = lane >> 4;    // 0..3
    const int lc   = lane & 15;    // 0..15
    const int q0   = blockIdx.x * 16;
    const int kv0  = w * KVSPLIT;

    // Q fragments: qa[dc] = Q[q0+lc][dc*32 + g*8 .. +7]
    half8 qa[4];
    {
        const _Float16* qrow = Qh + (q0 + lc) * D + g * 8;
#pragma unroll
        for (int dc = 0; dc < 4; ++dc)
            qa[dc] = *reinterpret_cast<const half8*>(qrow + dc * 32);
    }

    f32x4 oacc[8];
#pragma unroll
    for (int t = 0; t < 8; ++t) oacc[t] = (f32x4){0.f, 0.f, 0.f, 0.f};
    float mrun[4], lrun[4];
#pragma unroll
    for (int i = 0; i < 4; ++i) { mrun[i] = -1e30f; lrun[i] = 0.f; }

    _Float16* pw = plds[w];

    for (int kc = 0; kc < KVSPLIT; kc += KVBLK) {
        const int k0 = kv0 + kc;

        // ---- S = Q K^T for 4 k-tiles of 16 ----
        f32x4 s[4];
#pragma unroll
        for (int kt = 0; kt < 4; ++kt) {
            f32x4 acc = (f32x4){0.f, 0.f, 0.f, 0.f};
            const _Float16* krow = Kh + (k0 + kt * 16 + lc) * D + g * 8;
#pragma unroll
            for (int dc = 0; dc < 4; ++dc) {
                half8 kb = *reinterpret_cast<const half8*>(krow + dc * 32);
                acc = __builtin_amdgcn_mfma_f32_16x16x32_f16(qa[dc], kb, acc, 0, 0, 0);
            }
            s[kt] = acc;
        }

        // ---- online softmax ----
        float mc[4];
#pragma unroll
        for (int i = 0; i < 4; ++i) {
            float v = fmaxf(fmaxf(s[0][i], s[1][i]), fmaxf(s[2][i], s[3][i]));
            v = fmaxf(v, __shfl_xor(v, 1));
            v = fmaxf(v, __shfl_xor(v, 2));
            v = fmaxf(v, __shfl_xor(v, 4));
            v = fmaxf(v, __shfl_xor(v, 8));
            mc[i] = v;
        }
        float scl[4];
#pragma unroll
        for (int i = 0; i < 4; ++i) {
            float nm = fmaxf(mrun[i], mc[i]);
            scl[i] = __expf(mrun[i] - nm);
            mrun[i] = nm;
        }
        float rs[4] = {0.f, 0.f, 0.f, 0.f};
#pragma unroll
        for (int kt = 0; kt < 4; ++kt)
#pragma unroll
            for (int i = 0; i < 4; ++i) {
                float p = __expf(s[kt][i] - mrun[i]);
                s[kt][i] = p;
                rs[i] += p;
            }
#pragma unroll
        for (int i = 0; i < 4; ++i) {
            float v = rs[i];
            v += __shfl_xor(v, 1);
            v += __shfl_xor(v, 2);
            v += __shfl_xor(v, 4);
            v += __shfl_xor(v, 8);
            lrun[i] = lrun[i] * scl[i] + v;
        }
#pragma unroll
        for (int t = 0; t < 8; ++t)
#pragma unroll
            for (int i = 0; i < 4; ++i) oacc[t][i] *= scl[i];

        // ---- write P to LDS (transpose, XOR-swizzled) ----
#pragma unroll
        for (int kt = 0; kt < 4; ++kt)
#pragma unroll
            for (int i = 0; i < 4; ++i) {
                int prow = g * 4 + i;
                int pcol = kt * 16 + lc;
                int idx = (prow * 64 + pcol) ^ ((prow & 7) << 3);
                pw[idx] = (_Float16)(s[kt][i]);
            }

        // ---- O += P V ----
#pragma unroll
        for (int sc = 0; sc < 2; ++sc) {
            int base = (lc * 64 + sc * 32 + g * 8) ^ ((lc & 7) << 3);
            half8 pa = *reinterpret_cast<const half8*>(pw + base);
#pragma unroll
            for (int t = 0; t < 8; ++t) {
                half8 vb = *reinterpret_cast<const half8*>(
                    Vt + (t * 16 + lc) * N + k0 + sc * 32 + g * 8);
                oacc[t] = __builtin_amdgcn_mfma_f32_16x16x32_f16(pa, vb, oacc[t], 0, 0, 0);
            }
        }
    }

    // ---- write partials, merge across the 4 KV-split waves ----
#pragma unroll
    for (int t = 0; t < 8; ++t)
#pragma unroll
        for (int i = 0; i < 4; ++i)
            o_lds[w][g * 4 + i][t * 16 + lc] = oacc[t][i];
    if (lc == 0) {
#pragma unroll
        for (int i = 0; i < 4; ++i) {
            m_lds[w][g * 4 + i] = mrun[i];
            l_lds[w][g * 4 + i] = lrun[i];
        }
    }
    __syncthreads();

#pragma unroll
    for (int i = 0; i < 4; ++i) {
        int r = g * 4 + i;
        float M = m_lds[0][r];
#pragma unroll
        for (int ww = 1; ww < NWAVES; ++ww) M = fmaxf(M, m_lds[ww][r]);
        float e[NWAVES];
        float L = 0.f;
#pragma unroll
        for (int ww = 0; ww < NWAVES; ++ww) {
            e[ww] = __expf(m_lds[ww][r] - M);
            L += e[ww] * l_lds[ww][r];
        }
        float invL = 1.0f / L;
#pragma unroll
        for (int tt = 0; tt < 2; ++tt) {
            int t = w + tt * 4;
            float num = 0.f;
#pragma unroll
            for (int ww = 0; ww < NWAVES; ++ww)
                num += e[ww] * o_lds[ww][r][t * 16 + lc];
            O[(q0 + r) * D + t * 16 + lc] = num * invL;
        }
    }
}

extern "C" void kernel_launch(void* const* d_in, const int* in_sizes, int n_in,
                              void* d_out, int out_size, void* d_ws, size_t ws_size,
                              hipStream_t stream) {
    const float* Q = (const float*)d_in[0];
    const float* K = (const float*)d_in[1];
    const float* V = (const float*)d_in[2];
    float* O = (float*)d_out;

    _Float16* Qh = (_Float16*)d_ws;
    _Float16* Kh = Qh + N * D;
    _Float16* Vt = Kh + N * D;

    const int n4 = N * D / 4;  // 262144
    hipLaunchKernelGGL(cvt_f16_4, dim3(n4 / 256), dim3(256), 0, stream,
                       (const float4*)Q, Qh, n4);
    hipLaunchKernelGGL(cvt_f16_4, dim3(n4 / 256), dim3(256), 0, stream,
                       (const float4*)K, Kh, n4);
    hipLaunchKernelGGL(transpose_v, dim3(N / 64, D / 64), dim3(256), 0, stream, V, Vt);
    hipLaunchKernelGGL(fa_kernel, dim3(N / 16), dim3(256), 0, stream, Qh, Kh, Vt, O);
}

// Round 4
// 105.535 us; speedup vs baseline: 2.8448x; 2.8448x over previous
//
#include <hip/hip_runtime.h>
#include <hip/hip_bf16.h>

#define N 8192
#define D 128
#define NWAVES 4
#define NSPLIT 4
#define KVSPLIT (N / NSPLIT)      // 2048 keys per block
#define KVBLK 64
#define NT (KVSPLIT / KVBLK)      // 32 tiles

typedef __attribute__((ext_vector_type(8))) _Float16 half8;
typedef __attribute__((ext_vector_type(4))) float f32x4;

// ---- preprocessing: fp32 -> fp16 (row-major) ----
__global__ void cvt_f16_4(const float4* __restrict__ src, _Float16* __restrict__ dst, int n4) {
    int i = blockIdx.x * 256 + threadIdx.x;
    if (i < n4) {
        float4 v = src[i];
        _Float16 o0 = (_Float16)v.x, o1 = (_Float16)v.y, o2 = (_Float16)v.z, o3 = (_Float16)v.w;
        ushort4 o;
        o.x = __builtin_bit_cast(ushort, o0);
        o.y = __builtin_bit_cast(ushort, o1);
        o.z = __builtin_bit_cast(ushort, o2);
        o.w = __builtin_bit_cast(ushort, o3);
        *reinterpret_cast<ushort4*>(dst + i * 4) = o;
    }
}

// ---- preprocessing: V [N][D] fp32 -> Vt [D][N] fp16 (tiled transpose) ----
__global__ void transpose_v(const float* __restrict__ V, _Float16* __restrict__ Vt) {
    __shared__ _Float16 tile[64][65];
    const int k0 = blockIdx.x * 64;
    const int d0 = blockIdx.y * 64;
    const int tid = threadIdx.x;
#pragma unroll
    for (int p = 0; p < 16; ++p) {
        int flat = p * 256 + tid;
        int r = flat >> 6, c = flat & 63;
        tile[r][c] = (_Float16)(V[(k0 + r) * D + d0 + c]);
    }
    __syncthreads();
#pragma unroll
    for (int p = 0; p < 16; ++p) {
        int flat = p * 256 + tid;
        int dd = flat >> 6, k = flat & 63;
        Vt[(d0 + dd) * N + k0 + k] = tile[k][dd];
    }
}

// ---- stage one K/V tile (64 keys) into LDS, swizzled source, linear dest ----
// K tile: [64 key][128 d] fp16 -> 1024 x 16B chunks. Stored chunk (r, cst) holds
//   global chunk cc = (cst&8) | ((cst&7)^(r&7))  (involution; read applies same XOR)
// V tile: [128 d][64 key] fp16 -> 1024 chunks. Stored (d, sl) holds cc = sl^(d&7).
#define STAGE(kb_, vb_, k0_)                                                         \
    {                                                                                \
        _Pragma("unroll")                                                            \
        for (int p = 0; p < 4; ++p) {                                                \
            int c = (w * 256 + p * 64) + lane;                                       \
            int r = c >> 4, cst = c & 15;                                            \
            int cc = (cst & 8) | ((cst & 7) ^ (r & 7));                              \
            __builtin_amdgcn_global_load_lds(                                        \
                (const __attribute__((address_space(1))) void*)(Kh + (size_t)((k0_) + r) * D + cc * 8), \
                (__attribute__((address_space(3))) void*)((kb_) + (w * 256 + p * 64) * 8), 16, 0, 0);   \
        }                                                                            \
        _Pragma("unroll")                                                            \
        for (int p = 0; p < 4; ++p) {                                                \
            int c = (w * 256 + p * 64) + lane;                                       \
            int dd = c >> 3, sl = c & 7;                                             \
            int cc = sl ^ (dd & 7);                                                  \
            __builtin_amdgcn_global_load_lds(                                        \
                (const __attribute__((address_space(1))) void*)(Vt + (size_t)dd * N + (k0_) + cc * 8),  \
                (__attribute__((address_space(3))) void*)((vb_) + (w * 256 + p * 64) * 8), 16, 0, 0);   \
        }                                                                            \
    }

// ---- main kernel: 4 waves split Q (16 rows each), share staged KV tiles ----
// grid = (N/64, NSPLIT). Partials (normalized mean, m, l) -> workspace.
__launch_bounds__(256, 2)
__global__ void fa_kernel(const _Float16* __restrict__ Qh, const _Float16* __restrict__ Kh,
                          const _Float16* __restrict__ Vt, float* __restrict__ Opart,
                          float* __restrict__ Mpart, float* __restrict__ Lpart) {
    __shared__ _Float16 kbuf[2][64 * 128];     // 32 KB
    __shared__ _Float16 vbuf[2][128 * 64];     // 32 KB
    __shared__ _Float16 plds[NWAVES][16 * 64]; // 8 KB

    const int tid  = threadIdx.x;
    const int w    = tid >> 6;
    const int lane = tid & 63;
    const int g    = lane >> 4;    // 0..3
    const int lc   = lane & 15;    // 0..15
    const int l7   = lc & 7;
    const int q0   = blockIdx.x * 64 + w * 16;
    const int cchunk = blockIdx.y;
    const int kv0  = cchunk * KVSPLIT;

    // Q fragments: qa[dc] = Q[q0+lc][dc*32 + g*8 .. +7]
    half8 qa[4];
    {
        const _Float16* qrow = Qh + (size_t)(q0 + lc) * D + g * 8;
#pragma unroll
        for (int dc = 0; dc < 4; ++dc)
            qa[dc] = *reinterpret_cast<const half8*>(qrow + dc * 32);
    }

    f32x4 oacc[8];
#pragma unroll
    for (int t = 0; t < 8; ++t) oacc[t] = (f32x4){0.f, 0.f, 0.f, 0.f};
    float mrun[4], lrun[4];
#pragma unroll
    for (int i = 0; i < 4; ++i) { mrun[i] = -1e30f; lrun[i] = 0.f; }

    _Float16* pw = plds[w];

    // prologue: stage tile 0
    STAGE(kbuf[0], vbuf[0], kv0);
    __syncthreads();   // compiler drains vmcnt before s_barrier

    for (int t = 0; t < NT; ++t) {
        const int cur = t & 1;
        if (t + 1 < NT) STAGE(kbuf[cur ^ 1], vbuf[cur ^ 1], kv0 + (t + 1) * KVBLK);

        const _Float16* kb = kbuf[cur];
        const _Float16* vb = vbuf[cur];

        // ---- S = Q K^T for 4 k-tiles of 16 (K from LDS, swizzled) ----
        f32x4 s[4];
#pragma unroll
        for (int kt = 0; kt < 4; ++kt) {
            f32x4 acc = (f32x4){0.f, 0.f, 0.f, 0.f};
            const _Float16* krow = kb + (kt * 16 + lc) * 128;
#pragma unroll
            for (int dc = 0; dc < 4; ++dc) {
                int cc = dc * 4 + g;
                int pos = (cc & 8) | ((cc & 7) ^ l7);
                half8 kf = *reinterpret_cast<const half8*>(krow + pos * 8);
                acc = __builtin_amdgcn_mfma_f32_16x16x32_f16(qa[dc], kf, acc, 0, 0, 0);
            }
            s[kt] = acc;
        }

        // ---- online softmax ----
        float mc[4];
#pragma unroll
        for (int i = 0; i < 4; ++i) {
            float v = fmaxf(fmaxf(s[0][i], s[1][i]), fmaxf(s[2][i], s[3][i]));
            v = fmaxf(v, __shfl_xor(v, 1));
            v = fmaxf(v, __shfl_xor(v, 2));
            v = fmaxf(v, __shfl_xor(v, 4));
            v = fmaxf(v, __shfl_xor(v, 8));
            mc[i] = v;
        }
        float scl[4];
#pragma unroll
        for (int i = 0; i < 4; ++i) {
            float nm = fmaxf(mrun[i], mc[i]);
            scl[i] = __expf(mrun[i] - nm);
            mrun[i] = nm;
        }
        float rs[4] = {0.f, 0.f, 0.f, 0.f};
#pragma unroll
        for (int kt = 0; kt < 4; ++kt)
#pragma unroll
            for (int i = 0; i < 4; ++i) {
                float p = __expf(s[kt][i] - mrun[i]);
                s[kt][i] = p;
                rs[i] += p;
            }
#pragma unroll
        for (int i = 0; i < 4; ++i) {
            float v = rs[i];
            v += __shfl_xor(v, 1);
            v += __shfl_xor(v, 2);
            v += __shfl_xor(v, 4);
            v += __shfl_xor(v, 8);
            lrun[i] = lrun[i] * scl[i] + v;
        }
#pragma unroll
        for (int t8 = 0; t8 < 8; ++t8)
#pragma unroll
            for (int i = 0; i < 4; ++i) oacc[t8][i] *= scl[i];

        // ---- write P to LDS (transpose, XOR-swizzled) ----
#pragma unroll
        for (int kt = 0; kt < 4; ++kt)
#pragma unroll
            for (int i = 0; i < 4; ++i) {
                int prow = g * 4 + i;
                int pcol = kt * 16 + lc;
                int idx = (prow * 64 + pcol) ^ ((prow & 7) << 3);
                pw[idx] = (_Float16)(s[kt][i]);
            }

        // ---- O += P V (V from LDS, swizzled) ----
#pragma unroll
        for (int sc = 0; sc < 2; ++sc) {
            int base = (lc * 64 + sc * 32 + g * 8) ^ ((lc & 7) << 3);
            half8 pa = *reinterpret_cast<const half8*>(pw + base);
#pragma unroll
            for (int t8 = 0; t8 < 8; ++t8) {
                int pos = (sc * 4 + g) ^ l7;
                half8 vf = *reinterpret_cast<const half8*>(vb + (t8 * 16 + lc) * 64 + pos * 8);
                oacc[t8] = __builtin_amdgcn_mfma_f32_16x16x32_f16(pa, vf, oacc[t8], 0, 0, 0);
            }
        }

        __syncthreads();   // drains prefetch vmcnt + protects buffer reuse
    }

    // ---- epilogue: write normalized partial mean + (m, l) to workspace ----
    float invl[4];
#pragma unroll
    for (int i = 0; i < 4; ++i) invl[i] = 1.0f / lrun[i];
    const size_t base = (size_t)cchunk * N;
#pragma unroll
    for (int t8 = 0; t8 < 8; ++t8)
#pragma unroll
        for (int i = 0; i < 4; ++i)
            Opart[(base + q0 + g * 4 + i) * D + t8 * 16 + lc] = oacc[t8][i] * invl[i];
    if (lc == 0) {
#pragma unroll
        for (int i = 0; i < 4; ++i) {
            Mpart[base + q0 + g * 4 + i] = mrun[i];
            Lpart[base + q0 + g * 4 + i] = lrun[i];
        }
    }
}

// ---- merge the NSPLIT partials ----
__global__ void fa_merge(const float* __restrict__ Opart, const float* __restrict__ Mpart,
                         const float* __restrict__ Lpart, float* __restrict__ O) {
    int idx = blockIdx.x * 256 + threadIdx.x;   // over N*D
    int q = idx >> 7;
    int d = idx & 127;
    float m[NSPLIT], wgt[NSPLIT];
    float M = -1e30f;
#pragma unroll
    for (int c = 0; c < NSPLIT; ++c) {
        m[c] = Mpart[(size_t)c * N + q];
        M = fmaxf(M, m[c]);
    }
    float acc = 0.f, wsum = 0.f;
#pragma unroll
    for (int c = 0; c < NSPLIT; ++c) {
        wgt[c] = __expf(m[c] - M) * Lpart[(size_t)c * N + q];
        acc += wgt[c] * Opart[((size_t)c * N + q) * D + d];
        wsum += wgt[c];
    }
    O[idx] = acc / wsum;
}

extern "C" void kernel_launch(void* const* d_in, const int* in_sizes, int n_in,
                              void* d_out, int out_size, void* d_ws, size_t ws_size,
                              hipStream_t stream) {
    const float* Q = (const float*)d_in[0];
    const float* K = (const float*)d_in[1];
    const float* V = (const float*)d_in[2];
    float* O = (float*)d_out;

    _Float16* Qh = (_Float16*)d_ws;                 // 2 MB
    _Float16* Kh = Qh + (size_t)N * D;              // 2 MB
    _Float16* Vt = Kh + (size_t)N * D;              // 2 MB
    float* Opart = (float*)(Vt + (size_t)N * D);    // 16 MB
    float* Mpart = Opart + (size_t)NSPLIT * N * D;  // 128 KB
    float* Lpart = Mpart + (size_t)NSPLIT * N;      // 128 KB

    const int n4 = N * D / 4;
    hipLaunchKernelGGL(cvt_f16_4, dim3(n4 / 256), dim3(256), 0, stream,
                       (const float4*)Q, Qh, n4);
    hipLaunchKernelGGL(cvt_f16_4, dim3(n4 / 256), dim3(256), 0, stream,
                       (const float4*)K, Kh, n4);
    hipLaunchKernelGGL(transpose_v, dim3(N / 64, D / 64), dim3(256), 0, stream, V, Vt);
    hipLaunchKernelGGL(fa_kernel, dim3(N / 64, NSPLIT), dim3(256), 0, stream,
                       Qh, Kh, Vt, Opart, Mpart, Lpart);
    hipLaunchKernelGGL(fa_merge, dim3(N * D / 256), dim3(256), 0, stream,
                       Opart, Mpart, Lpart, O);
}